// Round 3
// baseline (1303.677 us; speedup 1.0000x reference)
//
#include <hip/hip_runtime.h>
#include <cstdint>
#include <math.h>

typedef _Float16 f16;
typedef __attribute__((ext_vector_type(4))) _Float16 f16x4;
typedef __attribute__((ext_vector_type(8))) _Float16 f16x8;
typedef __attribute__((ext_vector_type(4))) float f32x4;

// ---------------------------------------------------------------- helpers
__device__ inline void gload_lds16(const void* g, void* l) {
  auto gp = reinterpret_cast<const __attribute__((address_space(1))) uint32_t*>(
      reinterpret_cast<uintptr_t>(g));
  auto lp = reinterpret_cast<__attribute__((address_space(3))) uint32_t*>(
      reinterpret_cast<uintptr_t>(l));
  __builtin_amdgcn_global_load_lds(gp, lp, 16 /*bytes*/, 0, 0);
}

__device__ inline float wave_sum64(float v) {
#pragma unroll
  for (int m = 1; m < 64; m <<= 1) v += __shfl_xor(v, m);
  return v;
}

// ---------------------------------------------------------------- fp32 -> f16 convert
__global__ __launch_bounds__(256) void cvt_kernel(const float* __restrict__ src,
                                                  f16* __restrict__ dst, int n4) {
  int idx = blockIdx.x * blockDim.x + threadIdx.x;
  int stride = gridDim.x * blockDim.x;
  for (int i = idx; i < n4; i += stride) {
    float4 v = reinterpret_cast<const float4*>(src)[i];
    f16x4 h;
    h.x = (f16)v.x; h.y = (f16)v.y; h.z = (f16)v.z; h.w = (f16)v.w;
    reinterpret_cast<f16x4*>(dst)[i] = h;
  }
}

// ---------------------------------------------------------------- GEMM  C[M][N] = A[M][K] * B[N][K]^T
// 128x128 tile, BK=32, 4 waves (each a 64x64 quadrant), m97 structure + XCD swizzle.
template <bool MB>
__global__ __launch_bounds__(256, 2) void gemm_bt_f16(const f16* __restrict__ A,
                                                      const f16* __restrict__ Bw,
                                                      float* __restrict__ C,
                                                      int M, int N, int K) {
  __shared__ f16 As[2][128][32];
  __shared__ f16 Bs[2][128][32];
  const int tid = threadIdx.x;
  const int l = tid & 63, w = tid >> 6;
  const int lq = l & 15, lk = l >> 4;
  const int wr = w >> 1, wc = w & 1;
  // XCD-aware bijective swizzle (nwg % 8 == 0 for all our grids)
  const int nwg = gridDim.x * gridDim.y;
  const int p = blockIdx.y * gridDim.x + blockIdx.x;
  const int L = (p & 7) * (nwg >> 3) + (p >> 3);
  const int bx = L % gridDim.x, by = L / gridDim.x;
  const int brow = by * 128, bcol = bx * 128;
  const int srow = w * 16 + (l >> 2);   // staging row (+j*64)
  const int scol = (l & 3) * 8;         // staging col in f16 elems
  const int KT = K >> 5;

  f32x4 acc[4][4];
  f32x4 zf = {0.f, 0.f, 0.f, 0.f};
#pragma unroll
  for (int m = 0; m < 4; ++m)
#pragma unroll
    for (int n = 0; n < 4; ++n) acc[m][n] = zf;

  auto stage = [&](int kt, int buf) {
    const int k0 = kt * 32 + scol;
#pragma unroll
    for (int j = 0; j < 2; ++j) {
      int ra = brow + j * 64 + srow;
      if (MB) ra = (ra < M) ? ra : (M - 1);
      gload_lds16(A + (size_t)ra * K + k0,
                  (char*)(&As[buf][0][0]) + j * 4096 + w * 1024);
      int rb = bcol + j * 64 + srow;
      gload_lds16(Bw + (size_t)rb * K + k0,
                  (char*)(&Bs[buf][0][0]) + j * 4096 + w * 1024);
    }
  };

  stage(0, 0);
  for (int kt = 0; kt < KT; ++kt) {
    const int buf = kt & 1;
    __syncthreads();                 // drains vmcnt for stage(kt); also read/overwrite fence
    if (kt + 1 < KT) stage(kt + 1, buf ^ 1);  // prefetch overlaps this iter's compute
    f16x8 af[4], bf[4];
#pragma unroll
    for (int m = 0; m < 4; ++m)
      af[m] = *reinterpret_cast<const f16x8*>(&As[buf][wr * 64 + m * 16 + lq][lk * 8]);
#pragma unroll
    for (int n = 0; n < 4; ++n)
      bf[n] = *reinterpret_cast<const f16x8*>(&Bs[buf][wc * 64 + n * 16 + lq][lk * 8]);
#pragma unroll
    for (int m = 0; m < 4; ++m)
#pragma unroll
      for (int n = 0; n < 4; ++n)
        acc[m][n] = __builtin_amdgcn_mfma_f32_16x16x32_f16(af[m], bf[n], acc[m][n], 0, 0, 0);
  }

#pragma unroll
  for (int m = 0; m < 4; ++m) {
#pragma unroll
    for (int j = 0; j < 4; ++j) {
      int row = brow + wr * 64 + m * 16 + lk * 4 + j;
      if (MB && row >= M) continue;
      float* dst = C + (size_t)row * N + bcol + wc * 64 + lq;
#pragma unroll
      for (int n = 0; n < 4; ++n) dst[n * 16] = acc[m][n][j];
    }
  }
}

// ---------------------------------------------------------------- RMS-norm Q (scale + log2e folded), fp32 -> f16
__global__ __launch_bounds__(256) void rmsq_kernel(const float* __restrict__ Qraw,
                                                   const float* __restrict__ wq,
                                                   f16* __restrict__ Qf) {
  const int w = threadIdx.x >> 6, l = threadIdx.x & 63;
  const size_t row = (size_t)blockIdx.x * 4 + w;  // (token, head) row of 128
  const float* src = Qraw + row * 128;
  float2 x = reinterpret_cast<const float2*>(src)[l];
  float ss = wave_sum64(x.x * x.x + x.y * x.y);
  // scale = HD^-0.5 * log2(e) so attention can use exp2
  float rs = rsqrtf(ss * (1.0f / 128.0f) + 1e-5f) *
             (0.08838834764831845f * 1.4426950408889634f);
  float2 wv = reinterpret_cast<const float2*>(wq)[l];
  union { f16 h[2]; unsigned u; } pk;
  pk.h[0] = (f16)(x.x * rs * wv.x);
  pk.h[1] = (f16)(x.y * rs * wv.y);
  reinterpret_cast<unsigned*>(Qf + row * 128)[l] = pk.u;
}

// ---------------------------------------------------------------- K RMS-norm + V transpose scatter
// KVraw [6404][2048] fp32 -> Kf [b][kvh][1664][128] f16 (normed), Vtf [b][kvh][128][1664] f16
__global__ __launch_bounds__(256) void kvscatter_kernel(const float* __restrict__ KVraw,
                                                        const float* __restrict__ wk,
                                                        f16* __restrict__ Kf,
                                                        f16* __restrict__ Vtf) {
  const int w = threadIdx.x >> 6, l = threadIdx.x & 63;
  const int gw = blockIdx.x * 4 + w;  // 0..51231
  const int r = gw >> 3, kvh = gw & 7;
  const int b = r / 1601, s = r - b * 1601;
  const float* kr = KVraw + (size_t)r * 2048 + kvh * 128;
  float2 kx = reinterpret_cast<const float2*>(kr)[l];
  float ss = wave_sum64(kx.x * kx.x + kx.y * kx.y);
  float rs = rsqrtf(ss * (1.0f / 128.0f) + 1e-5f);
  float2 wv = reinterpret_cast<const float2*>(wk)[l];
  union { f16 h[2]; unsigned u; } pk;
  pk.h[0] = (f16)(kx.x * rs * wv.x);
  pk.h[1] = (f16)(kx.y * rs * wv.y);
  reinterpret_cast<unsigned*>(Kf + ((size_t)(b * 8 + kvh) * 1664 + s) * 128)[l] = pk.u;
  const float* vr = kr + 1024;
  float2 vx = reinterpret_cast<const float2*>(vr)[l];
  f16* vcol = Vtf + ((size_t)(b * 8 + kvh) * 128 + l * 2) * 1664 + s;
  vcol[0] = (f16)vx.x;
  vcol[1664] = (f16)vx.y;
}

// ---------------------------------------------------------------- flash attention (KVBLK=64, 32 KB LDS)
// Q [4096][4096] f16 (scale*log2e folded), Kf [b][kvh][1664][128], Vtf [b][kvh][128][1664]
// Oa [4096][4096] f16.  1-D grid of 1024 blocks, XCD-swizzled; 4 waves x 32 q rows.
__global__ __launch_bounds__(256, 4) void attn_kernel(const f16* __restrict__ Qf,
                                                      const f16* __restrict__ Kf,
                                                      const f16* __restrict__ Vtf,
                                                      f16* __restrict__ Oa) {
  __shared__ f16 Ksm[64][128];   // 16 KB, XOR-swizzled; re-used as P after QK^T
  __shared__ f16 Vsm[128][64];   // 16 KB, V^T tile [d][kv], XOR-swizzled (128 B rows)
  // XCD swizzle: physical p -> logical L so blocks sharing (b,kvh) share an XCD L2
  const int p = blockIdx.x;              // 0..1023
  const int L = (p & 7) * 128 + (p >> 3);
  const int qt = L & 7, h = (L >> 3) & 31, b = L >> 8;
  const int kvh = h >> 2;  // G = 4
  const int tid = threadIdx.x;
  const int l = tid & 63, w = tid >> 6;
  const int lq = l & 15, lk = l >> 4;

  // Q fragments in registers (reused across all 26 KV tiles)
  f16x8 qreg[2][4];
  const f16* Qbase = Qf + ((size_t)(b * 1024 + qt * 128 + w * 32)) * 4096 + h * 128;
#pragma unroll
  for (int qm = 0; qm < 2; ++qm)
#pragma unroll
    for (int ks = 0; ks < 4; ++ks)
      qreg[qm][ks] = *reinterpret_cast<const f16x8*>(
          Qbase + (size_t)(qm * 16 + lq) * 4096 + ks * 32 + lk * 8);

  const f16* Kb = Kf + (size_t)(b * 8 + kvh) * (1664 * 128);
  const f16* Vb = Vtf + (size_t)(b * 8 + kvh) * (128 * 1664);

  f32x4 o[2][8];
  f32x4 zf = {0.f, 0.f, 0.f, 0.f};
#pragma unroll
  for (int qm = 0; qm < 2; ++qm)
#pragma unroll
    for (int dn = 0; dn < 8; ++dn) o[qm][dn] = zf;
  float mrow[2][4], lrow[2][4];
#pragma unroll
  for (int qm = 0; qm < 2; ++qm)
#pragma unroll
    for (int j = 0; j < 4; ++j) { mrow[qm][j] = -1e30f; lrow[qm][j] = 0.f; }

  char* Pw = (char*)(&Ksm[0][0]) + w * 4096;  // per-wave 32q x 64kv alias of Ksm
  const int swzR = (lq & 7) << 4;

  for (int t = 0; t < 26; ++t) {
    // ---- stage K tile [64][128] (swizzled via pre-swizzled global source)
    // one gload_lds16 issue = 1024 B = 4 rows of 256 B
#pragma unroll
    for (int i = 0; i < 4; ++i) {
      int row = w * 16 + i * 4 + lk;
      int cb = (lq * 16) ^ ((row & 7) << 4);
      gload_lds16(Kb + (size_t)(t * 64 + row) * 128 + (cb >> 1),
                  (char*)(&Ksm[0][0]) + w * 4096 + i * 1024);
    }
    // ---- stage V^T tile [128][64] (swizzled)
    // one gload_lds16 issue = 1024 B = 8 rows of 128 B  -> base = w*4096 + i*1024
#pragma unroll
    for (int i = 0; i < 4; ++i) {
      int r = w * 32 + i * 8 + (l >> 3);
      int cb = ((l & 7) * 16) ^ ((r & 7) << 4);
      gload_lds16(Vb + (size_t)r * 1664 + t * 64 + (cb >> 1),
                  (char*)(&Vsm[0][0]) + w * 4096 + i * 1024);
    }
    __syncthreads();

    // ---- S = Q K^T (fp32 accum), wave's 32 q rows x 64 kv cols
    f32x4 s[2][4];
#pragma unroll
    for (int qm = 0; qm < 2; ++qm)
#pragma unroll
      for (int kn = 0; kn < 4; ++kn) s[qm][kn] = zf;
#pragma unroll
    for (int ks = 0; ks < 4; ++ks) {
      f16x8 bf[4];
#pragma unroll
      for (int kn = 0; kn < 4; ++kn)
        bf[kn] = *reinterpret_cast<const f16x8*>(
            (char*)(&Ksm[0][0]) + (kn * 16 + lq) * 256 + ((ks * 64 + lk * 16) ^ swzR));
#pragma unroll
      for (int qm = 0; qm < 2; ++qm)
#pragma unroll
        for (int kn = 0; kn < 4; ++kn)
          s[qm][kn] = __builtin_amdgcn_mfma_f32_16x16x32_f16(qreg[qm][ks], bf[kn], s[qm][kn], 0, 0, 0);
    }
    __syncthreads();  // all waves' Ksm reads done -> Ksm reusable as P

    // ---- mask tail (valid kv < 1601; tile 25 covers 1600..1663 -> local < 1)
    if (t == 25) {
#pragma unroll
      for (int kn = 0; kn < 4; ++kn) {
        bool valid = (kn * 16 + lq) < 1;
#pragma unroll
        for (int qm = 0; qm < 2; ++qm)
#pragma unroll
          for (int j = 0; j < 4; ++j) s[qm][kn][j] = valid ? s[qm][kn][j] : -1e30f;
      }
    }

    // ---- online softmax (log2 domain) + P write (f16, swizzled, into Ksm alias)
#pragma unroll
    for (int qm = 0; qm < 2; ++qm) {
#pragma unroll
      for (int j = 0; j < 4; ++j) {
        float mt = fmaxf(fmaxf(s[qm][0][j], s[qm][1][j]), fmaxf(s[qm][2][j], s[qm][3][j]));
        mt = fmaxf(mt, __shfl_xor(mt, 1));
        mt = fmaxf(mt, __shfl_xor(mt, 2));
        mt = fmaxf(mt, __shfl_xor(mt, 4));
        mt = fmaxf(mt, __shfl_xor(mt, 8));
        float mo = mrow[qm][j];
        float mn = fmaxf(mo, mt);
        float corr = exp2f(mo - mn);
        mrow[qm][j] = mn;
        float rsum = 0.f;
#pragma unroll
        for (int kn = 0; kn < 4; ++kn) {
          float pv = exp2f(s[qm][kn][j] - mn);
          s[qm][kn][j] = pv;
          rsum += pv;
        }
        rsum += __shfl_xor(rsum, 1);
        rsum += __shfl_xor(rsum, 2);
        rsum += __shfl_xor(rsum, 4);
        rsum += __shfl_xor(rsum, 8);
        lrow[qm][j] = lrow[qm][j] * corr + rsum;
#pragma unroll
        for (int dn = 0; dn < 8; ++dn) o[qm][dn][j] *= corr;
        int prow = qm * 16 + lk * 4 + j;
        int swzW = (prow & 7) << 4;
#pragma unroll
        for (int kn = 0; kn < 4; ++kn)
          *reinterpret_cast<f16*>(Pw + prow * 128 + (((kn * 16 + lq) * 2) ^ swzW)) =
              (f16)s[qm][kn][j];
      }
    }

    // ---- O += P V   (A = P from Ksm alias, B = V^T from Vsm, both swizzled b128)
#pragma unroll
    for (int c = 0; c < 2; ++c) {
      f16x8 pa[2];
#pragma unroll
      for (int qm = 0; qm < 2; ++qm)
        pa[qm] = *reinterpret_cast<const f16x8*>(
            Pw + (qm * 16 + lq) * 128 + ((c * 64 + lk * 16) ^ swzR));
      f16x8 vb[8];
#pragma unroll
      for (int dn = 0; dn < 8; ++dn)
        vb[dn] = *reinterpret_cast<const f16x8*>(
            (char*)(&Vsm[0][0]) + (dn * 16 + lq) * 128 + ((c * 64 + lk * 16) ^ swzR));
#pragma unroll
      for (int qm = 0; qm < 2; ++qm)
#pragma unroll
        for (int dn = 0; dn < 8; ++dn)
          o[qm][dn] = __builtin_amdgcn_mfma_f32_16x16x32_f16(pa[qm], vb[dn], o[qm][dn], 0, 0, 0);
    }
    __syncthreads();  // P/V reads done before next tile's staging overwrites
  }

  // ---- epilogue: O / l -> f16 attn output [token][feat]
#pragma unroll
  for (int qm = 0; qm < 2; ++qm) {
#pragma unroll
    for (int j = 0; j < 4; ++j) {
      float il = 1.0f / lrow[qm][j];
      int token = b * 1024 + qt * 128 + w * 32 + qm * 16 + lk * 4 + j;
      f16* dst = Oa + (size_t)token * 4096 + h * 128;
#pragma unroll
      for (int dn = 0; dn < 8; ++dn) dst[dn * 16 + lq] = (f16)(o[qm][dn][j] * il);
    }
  }
}

// ---------------------------------------------------------------- launch
extern "C" void kernel_launch(void* const* d_in, const int* in_sizes, int n_in,
                              void* d_out, int out_size, void* d_ws, size_t ws_size,
                              hipStream_t stream) {
  const float* hidden = (const float*)d_in[0];  // [4,1024,4096]
  const float* cross  = (const float*)d_in[1];  // [4,1601,4096]
  const float* wqkv   = (const float*)d_in[2];  // [6144,4096]
  const float* wo     = (const float*)d_in[3];  // [4096,4096]
  const float* qw     = (const float*)d_in[4];  // [128]
  const float* kw     = (const float*)d_in[5];  // [128]

  char* ws = (char*)d_ws;
  // region A: hidden_f16 (33.55 MB) -> later attn_f16
  f16* hidden_h = (f16*)(ws + 0);
  f16* attn_h   = hidden_h;
  // region B: wqkv_f16 (50.33 MB) -> later Q_f16
  f16* wqkv_h = (f16*)(ws + 33554432);
  f16* q_h    = wqkv_h;
  // region C: cross_f16 (52.46 MB) -> later K_f16 (13.63) + Vt_f16 (13.63)
  f16* cross_h = (f16*)(ws + 83886080);
  f16* k_h     = cross_h;
  f16* vt_h    = (f16*)(ws + 83886080 + 13631488);
  // region D: KVraw fp32 (52.46 MB) -> later wo_f16
  float* kvraw = (float*)(ws + 136347648);
  f16* wo_h    = (f16*)(ws + 136347648);
  // total ws use: 188,809,216 B
  float* qraw = (float*)d_out;  // d_out (67.1 MB fp32) doubles as Q-proj scratch

  // 1) converts needed before projections
  cvt_kernel<<<2048, 256, 0, stream>>>(hidden, hidden_h, 16777216 / 4);
  cvt_kernel<<<2048, 256, 0, stream>>>(cross, cross_h, 26230784 / 4);
  cvt_kernel<<<2048, 256, 0, stream>>>(wqkv, wqkv_h, 25165824 / 4);
  // 2) KV projection: cross @ wqkv[4096:6144]^T -> KVraw [6404][2048]
  gemm_bt_f16<true><<<dim3(16, 51), 256, 0, stream>>>(
      cross_h, wqkv_h + (size_t)4096 * 4096, kvraw, 6404, 2048, 4096);
  // 3) zero K/Vt pad cols (s in [1601,1664)), then scatter K (rms) + V (transpose)
  hipMemsetAsync(ws + 83886080, 0, 27262976, stream);
  kvscatter_kernel<<<12808, 256, 0, stream>>>(kvraw, kw, k_h, vt_h);
  // 4) wo convert (into dead KVraw region)
  cvt_kernel<<<2048, 256, 0, stream>>>(wo, wo_h, 16777216 / 4);
  // 5) Q projection -> fp32 scratch (d_out), then RMS-norm (+scale*log2e) -> f16
  gemm_bt_f16<false><<<dim3(32, 32), 256, 0, stream>>>(hidden_h, wqkv_h, qraw, 4096, 4096, 4096);
  rmsq_kernel<<<32768, 256, 0, stream>>>(qraw, qw, q_h);
  // 6) attention (1-D grid, XCD-swizzled in-kernel)
  attn_kernel<<<1024, 256, 0, stream>>>(q_h, k_h, vt_h, attn_h);
  // 7) output projection -> d_out
  gemm_bt_f16<false><<<dim3(32, 32), 256, 0, stream>>>(attn_h, wo_h, (float*)d_out, 4096, 4096, 4096);
}

// Round 4
// 893.106 us; speedup vs baseline: 1.4597x; 1.4597x over previous
//
#include <hip/hip_runtime.h>
#include <cstdint>
#include <math.h>

typedef _Float16 f16;
typedef __attribute__((ext_vector_type(4))) _Float16 f16x4;
typedef __attribute__((ext_vector_type(8))) _Float16 f16x8;
typedef __attribute__((ext_vector_type(4))) float f32x4;

// ---------------------------------------------------------------- helpers
__device__ inline void gload_lds16(const void* g, void* l) {
  auto gp = reinterpret_cast<const __attribute__((address_space(1))) uint32_t*>(
      reinterpret_cast<uintptr_t>(g));
  auto lp = reinterpret_cast<__attribute__((address_space(3))) uint32_t*>(
      reinterpret_cast<uintptr_t>(l));
  __builtin_amdgcn_global_load_lds(gp, lp, 16 /*bytes*/, 0, 0);
}

__device__ inline float wave_sum64(float v) {
#pragma unroll
  for (int m = 1; m < 64; m <<= 1) v += __shfl_xor(v, m);
  return v;
}

// ---------------------------------------------------------------- fp32 -> f16 convert
__global__ __launch_bounds__(256) void cvt_kernel(const float* __restrict__ src,
                                                  f16* __restrict__ dst, int n4) {
  int idx = blockIdx.x * blockDim.x + threadIdx.x;
  int stride = gridDim.x * blockDim.x;
  for (int i = idx; i < n4; i += stride) {
    float4 v = reinterpret_cast<const float4*>(src)[i];
    f16x4 h;
    h.x = (f16)v.x; h.y = (f16)v.y; h.z = (f16)v.z; h.w = (f16)v.w;
    reinterpret_cast<f16x4*>(dst)[i] = h;
  }
}

// ---------------------------------------------------------------- GEMM  C[M][N] = A[M][K] * B[N][K]^T
// 128x128 tile, BK=32, 4 waves (each a 64x64 quadrant), m97 structure + XCD swizzle.
template <bool MB>
__global__ __launch_bounds__(256, 2) void gemm_bt_f16(const f16* __restrict__ A,
                                                      const f16* __restrict__ Bw,
                                                      float* __restrict__ C,
                                                      int M, int N, int K) {
  __shared__ f16 As[2][128][32];
  __shared__ f16 Bs[2][128][32];
  const int tid = threadIdx.x;
  const int l = tid & 63, w = tid >> 6;
  const int lq = l & 15, lk = l >> 4;
  const int wr = w >> 1, wc = w & 1;
  // XCD-aware bijective swizzle (nwg % 8 == 0 for all our grids)
  const int nwg = gridDim.x * gridDim.y;
  const int p = blockIdx.y * gridDim.x + blockIdx.x;
  const int L = (p & 7) * (nwg >> 3) + (p >> 3);
  const int bx = L % gridDim.x, by = L / gridDim.x;
  const int brow = by * 128, bcol = bx * 128;
  const int srow = w * 16 + (l >> 2);   // staging row (+j*64)
  const int scol = (l & 3) * 8;         // staging col in f16 elems
  const int KT = K >> 5;

  f32x4 acc[4][4];
  f32x4 zf = {0.f, 0.f, 0.f, 0.f};
#pragma unroll
  for (int m = 0; m < 4; ++m)
#pragma unroll
    for (int n = 0; n < 4; ++n) acc[m][n] = zf;

  auto stage = [&](int kt, int buf) {
    const int k0 = kt * 32 + scol;
#pragma unroll
    for (int j = 0; j < 2; ++j) {
      int ra = brow + j * 64 + srow;
      if (MB) ra = (ra < M) ? ra : (M - 1);
      gload_lds16(A + (size_t)ra * K + k0,
                  (char*)(&As[buf][0][0]) + j * 4096 + w * 1024);
      int rb = bcol + j * 64 + srow;
      gload_lds16(Bw + (size_t)rb * K + k0,
                  (char*)(&Bs[buf][0][0]) + j * 4096 + w * 1024);
    }
  };

  stage(0, 0);
  for (int kt = 0; kt < KT; ++kt) {
    const int buf = kt & 1;
    __syncthreads();                 // drains vmcnt for stage(kt); also read/overwrite fence
    if (kt + 1 < KT) stage(kt + 1, buf ^ 1);  // prefetch overlaps this iter's compute
    f16x8 af[4], bf[4];
#pragma unroll
    for (int m = 0; m < 4; ++m)
      af[m] = *reinterpret_cast<const f16x8*>(&As[buf][wr * 64 + m * 16 + lq][lk * 8]);
#pragma unroll
    for (int n = 0; n < 4; ++n)
      bf[n] = *reinterpret_cast<const f16x8*>(&Bs[buf][wc * 64 + n * 16 + lq][lk * 8]);
#pragma unroll
    for (int m = 0; m < 4; ++m)
#pragma unroll
      for (int n = 0; n < 4; ++n)
        acc[m][n] = __builtin_amdgcn_mfma_f32_16x16x32_f16(af[m], bf[n], acc[m][n], 0, 0, 0);
  }

#pragma unroll
  for (int m = 0; m < 4; ++m) {
#pragma unroll
    for (int j = 0; j < 4; ++j) {
      int row = brow + wr * 64 + m * 16 + lk * 4 + j;
      if (MB && row >= M) continue;
      float* dst = C + (size_t)row * N + bcol + wc * 64 + lq;
#pragma unroll
      for (int n = 0; n < 4; ++n) dst[n * 16] = acc[m][n][j];
    }
  }
}

// ---------------------------------------------------------------- RMS-norm Q (scale + log2e folded), fp32 -> f16
__global__ __launch_bounds__(256) void rmsq_kernel(const float* __restrict__ Qraw,
                                                   const float* __restrict__ wq,
                                                   f16* __restrict__ Qf) {
  const int w = threadIdx.x >> 6, l = threadIdx.x & 63;
  const size_t row = (size_t)blockIdx.x * 4 + w;  // (token, head) row of 128
  const float* src = Qraw + row * 128;
  float2 x = reinterpret_cast<const float2*>(src)[l];
  float ss = wave_sum64(x.x * x.x + x.y * x.y);
  // scale = HD^-0.5 * log2(e) so attention can use exp2
  float rs = rsqrtf(ss * (1.0f / 128.0f) + 1e-5f) *
             (0.08838834764831845f * 1.4426950408889634f);
  float2 wv = reinterpret_cast<const float2*>(wq)[l];
  union { f16 h[2]; unsigned u; } pk;
  pk.h[0] = (f16)(x.x * rs * wv.x);
  pk.h[1] = (f16)(x.y * rs * wv.y);
  reinterpret_cast<unsigned*>(Qf + row * 128)[l] = pk.u;
}

// ---------------------------------------------------------------- K RMS-norm + V transpose scatter
// KVraw [6404][2048] fp32 -> Kf [b][kvh][1664][128] f16 (normed), Vtf [b][kvh][128][1664] f16
__global__ __launch_bounds__(256) void kvscatter_kernel(const float* __restrict__ KVraw,
                                                        const float* __restrict__ wk,
                                                        f16* __restrict__ Kf,
                                                        f16* __restrict__ Vtf) {
  const int w = threadIdx.x >> 6, l = threadIdx.x & 63;
  const int gw = blockIdx.x * 4 + w;  // 0..51231
  const int r = gw >> 3, kvh = gw & 7;
  const int b = r / 1601, s = r - b * 1601;
  const float* kr = KVraw + (size_t)r * 2048 + kvh * 128;
  float2 kx = reinterpret_cast<const float2*>(kr)[l];
  float ss = wave_sum64(kx.x * kx.x + kx.y * kx.y);
  float rs = rsqrtf(ss * (1.0f / 128.0f) + 1e-5f);
  float2 wv = reinterpret_cast<const float2*>(wk)[l];
  union { f16 h[2]; unsigned u; } pk;
  pk.h[0] = (f16)(kx.x * rs * wv.x);
  pk.h[1] = (f16)(kx.y * rs * wv.y);
  reinterpret_cast<unsigned*>(Kf + ((size_t)(b * 8 + kvh) * 1664 + s) * 128)[l] = pk.u;
  const float* vr = kr + 1024;
  float2 vx = reinterpret_cast<const float2*>(vr)[l];
  f16* vcol = Vtf + ((size_t)(b * 8 + kvh) * 128 + l * 2) * 1664 + s;
  vcol[0] = (f16)vx.x;
  vcol[1664] = (f16)vx.y;
}

// ---------------------------------------------------------------- flash attention (KVBLK=64, 32 KB LDS)
// Q [4096][4096] f16 (scale*log2e folded), Kf [b][kvh][1664][128], Vtf [b][kvh][128][1664]
// Oa [4096][4096] f16.  1-D grid of 1024 blocks, XCD-swizzled; 4 waves x 32 q rows.
// launch_bounds (256,2): 128-VGPR cap -- live state is ~128 VGPR; (256,4)'s 64-cap
// spilled 2.8 GB/dispatch to scratch (round-3 counters). Occupancy is then
// VGPR-limited at 16 waves/CU (4 blocks/CU) with 32 KB LDS.
__global__ __launch_bounds__(256, 2) void attn_kernel(const f16* __restrict__ Qf,
                                                      const f16* __restrict__ Kf,
                                                      const f16* __restrict__ Vtf,
                                                      f16* __restrict__ Oa) {
  __shared__ f16 Ksm[64][128];   // 16 KB, XOR-swizzled; re-used as P after QK^T
  __shared__ f16 Vsm[128][64];   // 16 KB, V^T tile [d][kv], XOR-swizzled (128 B rows)
  // XCD swizzle: physical p -> logical L so blocks sharing (b,kvh) share an XCD L2
  const int p = blockIdx.x;              // 0..1023
  const int L = (p & 7) * 128 + (p >> 3);
  const int qt = L & 7, h = (L >> 3) & 31, b = L >> 8;
  const int kvh = h >> 2;  // G = 4
  const int tid = threadIdx.x;
  const int l = tid & 63, w = tid >> 6;
  const int lq = l & 15, lk = l >> 4;

  // Q fragments in registers (reused across all 26 KV tiles)
  f16x8 qreg[2][4];
  const f16* Qbase = Qf + ((size_t)(b * 1024 + qt * 128 + w * 32)) * 4096 + h * 128;
#pragma unroll
  for (int qm = 0; qm < 2; ++qm)
#pragma unroll
    for (int ks = 0; ks < 4; ++ks)
      qreg[qm][ks] = *reinterpret_cast<const f16x8*>(
          Qbase + (size_t)(qm * 16 + lq) * 4096 + ks * 32 + lk * 8);

  const f16* Kb = Kf + (size_t)(b * 8 + kvh) * (1664 * 128);
  const f16* Vb = Vtf + (size_t)(b * 8 + kvh) * (128 * 1664);

  f32x4 o[2][8];
  f32x4 zf = {0.f, 0.f, 0.f, 0.f};
#pragma unroll
  for (int qm = 0; qm < 2; ++qm)
#pragma unroll
    for (int dn = 0; dn < 8; ++dn) o[qm][dn] = zf;
  float mrow[2][4], lrow[2][4];
#pragma unroll
  for (int qm = 0; qm < 2; ++qm)
#pragma unroll
    for (int j = 0; j < 4; ++j) { mrow[qm][j] = -1e30f; lrow[qm][j] = 0.f; }

  char* Pw = (char*)(&Ksm[0][0]) + w * 4096;  // per-wave 32q x 64kv alias of Ksm
  const int swzR = (lq & 7) << 4;

  for (int t = 0; t < 26; ++t) {
    // ---- stage K tile [64][128] (swizzled via pre-swizzled global source)
    // one gload_lds16 issue = 1024 B = 4 rows of 256 B
#pragma unroll
    for (int i = 0; i < 4; ++i) {
      int row = w * 16 + i * 4 + lk;
      int cb = (lq * 16) ^ ((row & 7) << 4);
      gload_lds16(Kb + (size_t)(t * 64 + row) * 128 + (cb >> 1),
                  (char*)(&Ksm[0][0]) + w * 4096 + i * 1024);
    }
    // ---- stage V^T tile [128][64] (swizzled)
    // one gload_lds16 issue = 1024 B = 8 rows of 128 B  -> base = w*4096 + i*1024
#pragma unroll
    for (int i = 0; i < 4; ++i) {
      int r = w * 32 + i * 8 + (l >> 3);
      int cb = ((l & 7) * 16) ^ ((r & 7) << 4);
      gload_lds16(Vb + (size_t)r * 1664 + t * 64 + (cb >> 1),
                  (char*)(&Vsm[0][0]) + w * 4096 + i * 1024);
    }
    __syncthreads();

    // ---- S = Q K^T (fp32 accum), wave's 32 q rows x 64 kv cols
    f32x4 s[2][4];
#pragma unroll
    for (int qm = 0; qm < 2; ++qm)
#pragma unroll
      for (int kn = 0; kn < 4; ++kn) s[qm][kn] = zf;
#pragma unroll
    for (int ks = 0; ks < 4; ++ks) {
      f16x8 bf[4];
#pragma unroll
      for (int kn = 0; kn < 4; ++kn)
        bf[kn] = *reinterpret_cast<const f16x8*>(
            (char*)(&Ksm[0][0]) + (kn * 16 + lq) * 256 + ((ks * 64 + lk * 16) ^ swzR));
#pragma unroll
      for (int qm = 0; qm < 2; ++qm)
#pragma unroll
        for (int kn = 0; kn < 4; ++kn)
          s[qm][kn] = __builtin_amdgcn_mfma_f32_16x16x32_f16(qreg[qm][ks], bf[kn], s[qm][kn], 0, 0, 0);
    }
    __syncthreads();  // all waves' Ksm reads done -> Ksm reusable as P

    // ---- mask tail (valid kv < 1601; tile 25 covers 1600..1663 -> local < 1)
    if (t == 25) {
#pragma unroll
      for (int kn = 0; kn < 4; ++kn) {
        bool valid = (kn * 16 + lq) < 1;
#pragma unroll
        for (int qm = 0; qm < 2; ++qm)
#pragma unroll
          for (int j = 0; j < 4; ++j) s[qm][kn][j] = valid ? s[qm][kn][j] : -1e30f;
      }
    }

    // ---- online softmax (log2 domain) + P write (f16, swizzled, into Ksm alias)
#pragma unroll
    for (int qm = 0; qm < 2; ++qm) {
#pragma unroll
      for (int j = 0; j < 4; ++j) {
        float mt = fmaxf(fmaxf(s[qm][0][j], s[qm][1][j]), fmaxf(s[qm][2][j], s[qm][3][j]));
        mt = fmaxf(mt, __shfl_xor(mt, 1));
        mt = fmaxf(mt, __shfl_xor(mt, 2));
        mt = fmaxf(mt, __shfl_xor(mt, 4));
        mt = fmaxf(mt, __shfl_xor(mt, 8));
        float mo = mrow[qm][j];
        float mn = fmaxf(mo, mt);
        float corr = exp2f(mo - mn);
        mrow[qm][j] = mn;
        float rsum = 0.f;
#pragma unroll
        for (int kn = 0; kn < 4; ++kn) {
          float pv = exp2f(s[qm][kn][j] - mn);
          s[qm][kn][j] = pv;
          rsum += pv;
        }
        rsum += __shfl_xor(rsum, 1);
        rsum += __shfl_xor(rsum, 2);
        rsum += __shfl_xor(rsum, 4);
        rsum += __shfl_xor(rsum, 8);
        lrow[qm][j] = lrow[qm][j] * corr + rsum;
#pragma unroll
        for (int dn = 0; dn < 8; ++dn) o[qm][dn][j] *= corr;
        int prow = qm * 16 + lk * 4 + j;
        int swzW = (prow & 7) << 4;
#pragma unroll
        for (int kn = 0; kn < 4; ++kn)
          *reinterpret_cast<f16*>(Pw + prow * 128 + (((kn * 16 + lq) * 2) ^ swzW)) =
              (f16)s[qm][kn][j];
      }
    }

    // ---- O += P V   (A = P from Ksm alias, B = V^T from Vsm, both swizzled b128)
#pragma unroll
    for (int c = 0; c < 2; ++c) {
      f16x8 pa[2];
#pragma unroll
      for (int qm = 0; qm < 2; ++qm)
        pa[qm] = *reinterpret_cast<const f16x8*>(
            Pw + (qm * 16 + lq) * 128 + ((c * 64 + lk * 16) ^ swzR));
      f16x8 vb[8];
#pragma unroll
      for (int dn = 0; dn < 8; ++dn)
        vb[dn] = *reinterpret_cast<const f16x8*>(
            (char*)(&Vsm[0][0]) + (dn * 16 + lq) * 128 + ((c * 64 + lk * 16) ^ swzR));
#pragma unroll
      for (int qm = 0; qm < 2; ++qm)
#pragma unroll
        for (int dn = 0; dn < 8; ++dn)
          o[qm][dn] = __builtin_amdgcn_mfma_f32_16x16x32_f16(pa[qm], vb[dn], o[qm][dn], 0, 0, 0);
    }
    __syncthreads();  // P/V reads done before next tile's staging overwrites
  }

  // ---- epilogue: O / l -> f16 attn output [token][feat]
#pragma unroll
  for (int qm = 0; qm < 2; ++qm) {
#pragma unroll
    for (int j = 0; j < 4; ++j) {
      float il = 1.0f / lrow[qm][j];
      int token = b * 1024 + qt * 128 + w * 32 + qm * 16 + lk * 4 + j;
      f16* dst = Oa + (size_t)token * 4096 + h * 128;
#pragma unroll
      for (int dn = 0; dn < 8; ++dn) dst[dn * 16 + lq] = (f16)(o[qm][dn][j] * il);
    }
  }
}

// ---------------------------------------------------------------- launch
extern "C" void kernel_launch(void* const* d_in, const int* in_sizes, int n_in,
                              void* d_out, int out_size, void* d_ws, size_t ws_size,
                              hipStream_t stream) {
  const float* hidden = (const float*)d_in[0];  // [4,1024,4096]
  const float* cross  = (const float*)d_in[1];  // [4,1601,4096]
  const float* wqkv   = (const float*)d_in[2];  // [6144,4096]
  const float* wo     = (const float*)d_in[3];  // [4096,4096]
  const float* qw     = (const float*)d_in[4];  // [128]
  const float* kw     = (const float*)d_in[5];  // [128]

  char* ws = (char*)d_ws;
  // region A: hidden_f16 (33.55 MB) -> later attn_f16
  f16* hidden_h = (f16*)(ws + 0);
  f16* attn_h   = hidden_h;
  // region B: wqkv_f16 (50.33 MB) -> later Q_f16
  f16* wqkv_h = (f16*)(ws + 33554432);
  f16* q_h    = wqkv_h;
  // region C: cross_f16 (52.46 MB) -> later K_f16 (13.63) + Vt_f16 (13.63)
  f16* cross_h = (f16*)(ws + 83886080);
  f16* k_h     = cross_h;
  f16* vt_h    = (f16*)(ws + 83886080 + 13631488);
  // region D: KVraw fp32 (52.46 MB) -> later wo_f16
  float* kvraw = (float*)(ws + 136347648);
  f16* wo_h    = (f16*)(ws + 136347648);
  // total ws use: 188,809,216 B
  float* qraw = (float*)d_out;  // d_out (67.1 MB fp32) doubles as Q-proj scratch

  // 1) converts needed before projections
  cvt_kernel<<<2048, 256, 0, stream>>>(hidden, hidden_h, 16777216 / 4);
  cvt_kernel<<<2048, 256, 0, stream>>>(cross, cross_h, 26230784 / 4);
  cvt_kernel<<<2048, 256, 0, stream>>>(wqkv, wqkv_h, 25165824 / 4);
  // 2) KV projection: cross @ wqkv[4096:6144]^T -> KVraw [6404][2048]
  gemm_bt_f16<true><<<dim3(16, 51), 256, 0, stream>>>(
      cross_h, wqkv_h + (size_t)4096 * 4096, kvraw, 6404, 2048, 4096);
  // 3) zero K/Vt pad cols (s in [1601,1664)), then scatter K (rms) + V (transpose)
  hipMemsetAsync(ws + 83886080, 0, 27262976, stream);
  kvscatter_kernel<<<12808, 256, 0, stream>>>(kvraw, kw, k_h, vt_h);
  // 4) wo convert (into dead KVraw region)
  cvt_kernel<<<2048, 256, 0, stream>>>(wo, wo_h, 16777216 / 4);
  // 5) Q projection -> fp32 scratch (d_out), then RMS-norm (+scale*log2e) -> f16
  gemm_bt_f16<false><<<dim3(32, 32), 256, 0, stream>>>(hidden_h, wqkv_h, qraw, 4096, 4096, 4096);
  rmsq_kernel<<<32768, 256, 0, stream>>>(qraw, qw, q_h);
  // 6) attention (1-D grid, XCD-swizzled in-kernel)
  attn_kernel<<<1024, 256, 0, stream>>>(q_h, k_h, vt_h, attn_h);
  // 7) output projection -> d_out
  gemm_bt_f16<false><<<dim3(32, 32), 256, 0, stream>>>(attn_h, wo_h, (float*)d_out, 4096, 4096, 4096);
}